// Round 2
// baseline (1294.291 us; speedup 1.0000x reference)
//
#include <hip/hip_runtime.h>

#define N_USERS 100000
#define N_ITEMS 50000
#define DIM     64
#define N_NODES (N_USERS + N_ITEMS + 1)   /* 150001 */
#define N_EDGES 4800000

static constexpr long long NF = (long long)N_NODES * DIM;   // 9,600,064 floats per tensor

// ------------------- scan geometry -------------------
#define SCAN_T      256
#define SCAN_ITEMS  8
#define SCAN_CHUNK  (SCAN_T * SCAN_ITEMS)                    /* 2048 */
#define SCAN_NBLK   ((N_NODES + SCAN_CHUNK - 1) / SCAN_CHUNK) /* 74 */

// ---------------------------------------------------------------------------
// zero-fill for deg (replaces hipMemsetAsync in the capture path)
// ---------------------------------------------------------------------------
__global__ void zero_kernel(int* __restrict__ p, int n) {
    int i = blockIdx.x * blockDim.x + threadIdx.x;
    if (i < n) p[i] = 0;
}

// ---------------------------------------------------------------------------
// ego = concat(user_emb, item_emb)  (float4-vectorized)
// ---------------------------------------------------------------------------
__global__ void concat_kernel(const float4* __restrict__ user,
                              const float4* __restrict__ item,
                              float4* __restrict__ ego) {
    int i = blockIdx.x * blockDim.x + threadIdx.x;
    const int userF4 = N_USERS * DIM / 4;
    const int totF4  = (int)(NF / 4);
    if (i < userF4)      ego[i] = user[i];
    else if (i < totF4)  ego[i] = item[i - userF4];
}

// ---------------------------------------------------------------------------
// CSR build step 1: histogram of rows
// ---------------------------------------------------------------------------
__global__ void hist_kernel(const int* __restrict__ rows, int* __restrict__ deg) {
    int e = blockIdx.x * blockDim.x + threadIdx.x;
    if (e < N_EDGES) atomicAdd(&deg[rows[e]], 1);
}

// ---------------------------------------------------------------------------
// CSR build step 2a: per-block partial sums of deg (74 blocks x 2048 elems)
// ---------------------------------------------------------------------------
__global__ void __launch_bounds__(SCAN_T)
scan_a_kernel(const int* __restrict__ deg, int* __restrict__ bsum) {
    __shared__ int lds[SCAN_T];
    int b = blockIdx.x, t = threadIdx.x;
    int base = b * SCAN_CHUNK + t * SCAN_ITEMS;
    int s = 0;
    #pragma unroll
    for (int i = 0; i < SCAN_ITEMS; ++i) {
        int idx = base + i;
        s += (idx < N_NODES) ? deg[idx] : 0;
    }
    lds[t] = s;
    __syncthreads();
    for (int off = SCAN_T / 2; off > 0; off >>= 1) {
        if (t < off) lds[t] += lds[t + off];
        __syncthreads();
    }
    if (t == 0) bsum[b] = lds[0];
}

// ---------------------------------------------------------------------------
// CSR build step 2b: exclusive scan of the 74 block sums (one tiny block)
// ---------------------------------------------------------------------------
__global__ void __launch_bounds__(128)
scan_b_kernel(const int* __restrict__ bsum, int* __restrict__ boff) {
    __shared__ int lds[128];
    int t = threadIdx.x;
    lds[t] = (t < SCAN_NBLK) ? bsum[t] : 0;
    __syncthreads();
    for (int off = 1; off < 128; off <<= 1) {
        int x = lds[t];
        int y = (t >= off) ? lds[t - off] : 0;
        __syncthreads();
        lds[t] = x + y;
        __syncthreads();
    }
    if (t < SCAN_NBLK) boff[t] = (t == 0) ? 0 : lds[t - 1];
}

// ---------------------------------------------------------------------------
// CSR build step 2c: block-local exclusive scan + block offset -> row_ptr,cursor
// ---------------------------------------------------------------------------
__global__ void __launch_bounds__(SCAN_T)
scan_c_kernel(const int* __restrict__ deg, const int* __restrict__ boff,
              int* __restrict__ row_ptr, int* __restrict__ cursor) {
    __shared__ int lds[SCAN_T];
    int b = blockIdx.x, t = threadIdx.x;
    int base = b * SCAN_CHUNK + t * SCAN_ITEMS;
    int v[SCAN_ITEMS];
    int s = 0;
    #pragma unroll
    for (int i = 0; i < SCAN_ITEMS; ++i) {
        int idx = base + i;
        int d = (idx < N_NODES) ? deg[idx] : 0;
        v[i] = s;                 // exclusive prefix within thread
        s += d;
    }
    lds[t] = s;
    __syncthreads();
    // Hillis-Steele inclusive scan over the 256 thread sums
    for (int off = 1; off < SCAN_T; off <<= 1) {
        int x = lds[t];
        int y = (t >= off) ? lds[t - off] : 0;
        __syncthreads();
        lds[t] = x + y;
        __syncthreads();
    }
    int toff = ((t == 0) ? 0 : lds[t - 1]) + boff[b];
    #pragma unroll
    for (int i = 0; i < SCAN_ITEMS; ++i) {
        int idx = base + i;
        if (idx < N_NODES) {
            int val = v[i] + toff;
            row_ptr[idx] = val;
            cursor[idx]  = val;
        }
    }
    if (b == 0 && t == 0) row_ptr[N_NODES] = N_EDGES;
}

// ---------------------------------------------------------------------------
// CSR build step 3: scatter edges, packed (col, val-bits) as one uint2 store
// ---------------------------------------------------------------------------
__global__ void scatter_kernel(const int* __restrict__ rows,
                               const int* __restrict__ cols,
                               const float* __restrict__ vals,
                               int* __restrict__ cursor,
                               uint2* __restrict__ edges) {
    int e = blockIdx.x * blockDim.x + threadIdx.x;
    if (e < N_EDGES) {
        int r = rows[e];
        int p = atomicAdd(&cursor[r], 1);
        edges[p] = make_uint2((unsigned)cols[e], __float_as_uint(vals[e]));
    }
}

// ---------------------------------------------------------------------------
// CSR SpMM: one wave per row; lane d owns dim d.
// 8-deep unrolled gathers: 8 independent load->FMA chains per iteration to
// halve the number of latency-exposed stall windows vs the 4-deep version
// (avg degree 32 -> 4 main-loop iterations instead of 8).
// ---------------------------------------------------------------------------
__global__ void __launch_bounds__(256)
spmm_csr_kernel(const int* __restrict__ row_ptr,
                const uint2* __restrict__ edges,
                const float* __restrict__ hin,
                float* __restrict__ hout) {
    int wave = (blockIdx.x * blockDim.x + threadIdx.x) >> 6;
    int lane = threadIdx.x & 63;
    if (wave >= N_NODES) return;
    int start = row_ptr[wave];
    int end   = row_ptr[wave + 1];
    float a0 = 0.f, a1 = 0.f, a2 = 0.f, a3 = 0.f;
    float a4 = 0.f, a5 = 0.f, a6 = 0.f, a7 = 0.f;
    int e = start;
    for (; e + 8 <= end; e += 8) {
        uint2 e0 = edges[e],     e1 = edges[e + 1], e2 = edges[e + 2], e3 = edges[e + 3];
        uint2 e4 = edges[e + 4], e5 = edges[e + 5], e6 = edges[e + 6], e7 = edges[e + 7];
        a0 += __uint_as_float(e0.y) * hin[(int)e0.x * DIM + lane];
        a1 += __uint_as_float(e1.y) * hin[(int)e1.x * DIM + lane];
        a2 += __uint_as_float(e2.y) * hin[(int)e2.x * DIM + lane];
        a3 += __uint_as_float(e3.y) * hin[(int)e3.x * DIM + lane];
        a4 += __uint_as_float(e4.y) * hin[(int)e4.x * DIM + lane];
        a5 += __uint_as_float(e5.y) * hin[(int)e5.x * DIM + lane];
        a6 += __uint_as_float(e6.y) * hin[(int)e6.x * DIM + lane];
        a7 += __uint_as_float(e7.y) * hin[(int)e7.x * DIM + lane];
    }
    for (; e + 4 <= end; e += 4) {
        uint2 e0 = edges[e], e1 = edges[e + 1], e2 = edges[e + 2], e3 = edges[e + 3];
        a0 += __uint_as_float(e0.y) * hin[(int)e0.x * DIM + lane];
        a1 += __uint_as_float(e1.y) * hin[(int)e1.x * DIM + lane];
        a2 += __uint_as_float(e2.y) * hin[(int)e2.x * DIM + lane];
        a3 += __uint_as_float(e3.y) * hin[(int)e3.x * DIM + lane];
    }
    for (; e < end; ++e) {
        uint2 ed = edges[e];
        a0 += __uint_as_float(ed.y) * hin[(int)ed.x * DIM + lane];
    }
    hout[wave * DIM + lane] = ((a0 + a1) + (a2 + a3)) + ((a4 + a5) + (a6 + a7));
}

// ---------------------------------------------------------------------------
// CSR SpMM (last layer) fused with h_sum = ego + h1 + h2 + h3
// ---------------------------------------------------------------------------
__global__ void __launch_bounds__(256)
spmm_csr_fused_kernel(const int* __restrict__ row_ptr,
                      const uint2* __restrict__ edges,
                      const float* __restrict__ h2,      // gather source
                      const float* __restrict__ ego,
                      const float* __restrict__ h1,
                      float* __restrict__ h3,
                      float* __restrict__ hsum) {
    int wave = (blockIdx.x * blockDim.x + threadIdx.x) >> 6;
    int lane = threadIdx.x & 63;
    if (wave >= N_NODES) return;
    int start = row_ptr[wave];
    int end   = row_ptr[wave + 1];
    float a0 = 0.f, a1 = 0.f, a2 = 0.f, a3 = 0.f;
    float a4 = 0.f, a5 = 0.f, a6 = 0.f, a7 = 0.f;
    int e = start;
    for (; e + 8 <= end; e += 8) {
        uint2 e0 = edges[e],     e1 = edges[e + 1], e2 = edges[e + 2], e3 = edges[e + 3];
        uint2 e4 = edges[e + 4], e5 = edges[e + 5], e6 = edges[e + 6], e7 = edges[e + 7];
        a0 += __uint_as_float(e0.y) * h2[(int)e0.x * DIM + lane];
        a1 += __uint_as_float(e1.y) * h2[(int)e1.x * DIM + lane];
        a2 += __uint_as_float(e2.y) * h2[(int)e2.x * DIM + lane];
        a3 += __uint_as_float(e3.y) * h2[(int)e3.x * DIM + lane];
        a4 += __uint_as_float(e4.y) * h2[(int)e4.x * DIM + lane];
        a5 += __uint_as_float(e5.y) * h2[(int)e5.x * DIM + lane];
        a6 += __uint_as_float(e6.y) * h2[(int)e6.x * DIM + lane];
        a7 += __uint_as_float(e7.y) * h2[(int)e7.x * DIM + lane];
    }
    for (; e + 4 <= end; e += 4) {
        uint2 e0 = edges[e], e1 = edges[e + 1], e2 = edges[e + 2], e3 = edges[e + 3];
        a0 += __uint_as_float(e0.y) * h2[(int)e0.x * DIM + lane];
        a1 += __uint_as_float(e1.y) * h2[(int)e1.x * DIM + lane];
        a2 += __uint_as_float(e2.y) * h2[(int)e2.x * DIM + lane];
        a3 += __uint_as_float(e3.y) * h2[(int)e3.x * DIM + lane];
    }
    for (; e < end; ++e) {
        uint2 ed = edges[e];
        a0 += __uint_as_float(ed.y) * h2[(int)ed.x * DIM + lane];
    }
    float acc = ((a0 + a1) + (a2 + a3)) + ((a4 + a5) + (a6 + a7));
    int o = wave * DIM + lane;
    h3[o]   = acc;
    hsum[o] = ego[o] + h1[o] + h2[o] + acc;
}

// ---------------------------------------------------------------------------
// Fallback SpMM via fp32 atomics (used only if ws_size too small for CSR)
// ---------------------------------------------------------------------------
__global__ void spmm_atomic_kernel(const int* __restrict__ rows,
                                   const int* __restrict__ cols,
                                   const float* __restrict__ vals,
                                   const float* __restrict__ hin,
                                   float* __restrict__ hout) {
    int e = blockIdx.x * 4 + (threadIdx.x >> 6);
    int d = threadIdx.x & 63;
    if (e < N_EDGES) {
        atomicAdd(&hout[rows[e] * DIM + d], vals[e] * hin[cols[e] * DIM + d]);
    }
}

__global__ void zero_f_kernel(float* __restrict__ p, long long n) {
    long long i = (long long)blockIdx.x * blockDim.x + threadIdx.x;
    if (i < n) p[i] = 0.f;
}

__global__ void sum_kernel(const float4* __restrict__ a,
                           const float4* __restrict__ b,
                           const float4* __restrict__ c,
                           const float4* __restrict__ d,
                           float4* __restrict__ out) {
    int i = blockIdx.x * blockDim.x + threadIdx.x;
    if (i < (int)(NF / 4)) {
        float4 x = a[i], y = b[i], z = c[i], w = d[i];
        out[i] = make_float4(x.x + y.x + z.x + w.x,
                             x.y + y.y + z.y + w.y,
                             x.z + y.z + z.z + w.z,
                             x.w + y.w + z.w + w.w);
    }
}

extern "C" void kernel_launch(void* const* d_in, const int* in_sizes, int n_in,
                              void* d_out, int out_size, void* d_ws, size_t ws_size,
                              hipStream_t stream) {
    const float* user = (const float*)d_in[0];
    const float* item = (const float*)d_in[1];
    const float* vals = (const float*)d_in[2];
    const int*   rows = (const int*)d_in[3];
    const int*   cols = (const int*)d_in[4];

    float* out  = (float*)d_out;
    float* hsum = out;
    float* ego  = out + NF;
    float* h1   = out + 2 * NF;
    float* h2   = out + 3 * NF;
    float* h3   = out + 4 * NF;

    const int totF4 = (int)(NF / 4);

    concat_kernel<<<(totF4 + 255) / 256, 256, 0, stream>>>(
        (const float4*)user, (const float4*)item, (float4*)ego);

    // workspace layout: edges first (8B aligned), then int arrays
    const size_t nInt = (size_t)(N_NODES + 2);
    size_t need = (size_t)N_EDGES * 8 + (3 * nInt + 2 * 128) * 4;   // ~40.2 MB

    if (ws_size >= need) {
        uint2* edges   = (uint2*)d_ws;
        int*   deg     = (int*)(edges + N_EDGES);
        int*   row_ptr = deg + nInt;
        int*   cursor  = row_ptr + nInt;
        int*   bsum    = cursor + nInt;
        int*   boff    = bsum + 128;

        zero_kernel<<<(N_NODES + 255) / 256, 256, 0, stream>>>(deg, N_NODES);
        hist_kernel<<<(N_EDGES + 255) / 256, 256, 0, stream>>>(rows, deg);
        scan_a_kernel<<<SCAN_NBLK, SCAN_T, 0, stream>>>(deg, bsum);
        scan_b_kernel<<<1, 128, 0, stream>>>(bsum, boff);
        scan_c_kernel<<<SCAN_NBLK, SCAN_T, 0, stream>>>(deg, boff, row_ptr, cursor);
        scatter_kernel<<<(N_EDGES + 255) / 256, 256, 0, stream>>>(
            rows, cols, vals, cursor, edges);

        const int spmmBlocks = (N_NODES * 64 + 255) / 256;  // 1 wave per row
        spmm_csr_kernel<<<spmmBlocks, 256, 0, stream>>>(row_ptr, edges, ego, h1);
        spmm_csr_kernel<<<spmmBlocks, 256, 0, stream>>>(row_ptr, edges, h1,  h2);
        spmm_csr_fused_kernel<<<spmmBlocks, 256, 0, stream>>>(
            row_ptr, edges, h2, ego, h1, h3, hsum);
    } else {
        const long long nz = 3 * NF;
        zero_f_kernel<<<(int)((nz + 255) / 256), 256, 0, stream>>>(h1, nz);
        const int ablocks = (N_EDGES + 3) / 4;
        spmm_atomic_kernel<<<ablocks, 256, 0, stream>>>(rows, cols, vals, ego, h1);
        spmm_atomic_kernel<<<ablocks, 256, 0, stream>>>(rows, cols, vals, h1,  h2);
        spmm_atomic_kernel<<<ablocks, 256, 0, stream>>>(rows, cols, vals, h2,  h3);
        sum_kernel<<<(totF4 + 255) / 256, 256, 0, stream>>>(
            (const float4*)ego, (const float4*)h1, (const float4*)h2, (const float4*)h3,
            (float4*)hsum);
    }
}